// Round 15
// baseline (303.917 us; speedup 1.0000x reference)
//
#include <hip/hip_runtime.h>
#include <math.h>

#define PI_F 3.14159265358979323846f
#define NPIX 262144   // 512*512

typedef __attribute__((ext_vector_type(8))) short sh8;
typedef __attribute__((ext_vector_type(4))) float fx4;
typedef __attribute__((ext_vector_type(4))) unsigned short ush4;

__device__ __forceinline__ unsigned short f2bf(float v) {
    unsigned u = __float_as_uint(v);
    return (unsigned short)((u + 0x7FFFu + ((u >> 16) & 1)) >> 16);
}
__device__ __forceinline__ float bf2f(unsigned short h) {
    return __uint_as_float((unsigned)h << 16);
}

__device__ __forceinline__ int refl512(int t) {
    if (t < 0) t = -t;
    if (t > 511) t = 1022 - t;
    return t;
}

// ---------------------------------------------------------------- prep helpers (device)
__device__ __forceinline__ void prep_one(const float* __restrict__ w, unsigned short* __restrict__ h,
                                         unsigned short* __restrict__ l, int N, int K, int cshift, int idx) {
    if (idx >= N * K) return;
    int n = idx / K, kord = idx - n * K;
    int ksrc = kord;
    if (cshift) {
        int dydx = kord >> cshift, c = kord & ((1 << cshift) - 1);
        ksrc = c * 4 + dydx;
    }
    float v = w[n * K + ksrc];
    unsigned short hb = f2bf(v);
    h[idx] = hb;
    if (l) l[idx] = f2bf(v - bf2f(hb));
}

// ---------------------------------------------------------------- MEGA prep: weights + DFT tables + composes + dark channel
__global__ __launch_bounds__(256) void k_prep(
    const float* __restrict__ x, float* __restrict__ dark, float* __restrict__ blockmax,
    const float* __restrict__ w_d2, unsigned short* __restrict__ d2h, unsigned short* __restrict__ d2l,
    const float* __restrict__ w_a1, unsigned short* __restrict__ a1h, unsigned short* __restrict__ a1l,
    const float* __restrict__ w_a2, unsigned short* __restrict__ a2h, unsigned short* __restrict__ a2l,
    const float* __restrict__ w_s1, unsigned short* __restrict__ s1h,
    unsigned short* __restrict__ BfH, unsigned short* __restrict__ BfL,
    unsigned short* __restrict__ BfcH, unsigned short* __restrict__ BfcL,
    unsigned short* __restrict__ BicH, unsigned short* __restrict__ BicL,
    float* __restrict__ Birf, float* __restrict__ zbias,
    const float* __restrict__ w_e1, const float* __restrict__ b_e1,
    const float* __restrict__ w_e2, const float* __restrict__ b_e2,
    const float* __restrict__ w_d1, const float* __restrict__ b_d1,
    unsigned short* __restrict__ d1ch, float* __restrict__ b1c,
    const float* __restrict__ w_u3, const float* __restrict__ w_u4,
    const float* __restrict__ b_u3, const float* __restrict__ b_u4,
    const float* __restrict__ wsp2, const float* __restrict__ bsp2,
    unsigned short* __restrict__ Wg, float* __restrict__ bgc,
    const float* __restrict__ w2, const float* __restrict__ b2,
    const float* __restrict__ w3, const float* __restrict__ b3,
    const float* __restrict__ wu2, const float* __restrict__ bu2,
    const float* __restrict__ wu1, const float* __restrict__ bu1,
    float* __restrict__ Wc, float* __restrict__ bc,
    float* __restrict__ W21c, float* __restrict__ b21c) {
    __shared__ float smem[8448];   // rm[7680] | cm[512] | red[256] (branch-aliased)
    int b = blockIdx.x, tid = threadIdx.x;
    if (b < 512)       { prep_one(w_d2, d2h, d2l, 256, 512, 7, b * 256 + tid); return; }
    else if (b < 768)  { prep_one(w_a1, a1h, a1l, 256, 256, 0, (b - 512) * 256 + tid); return; }
    else if (b < 1024) { prep_one(w_a2, a2h, a2l, 256, 256, 0, (b - 768) * 256 + tid); return; }
    else if (b < 1280) { prep_one(w_s1, s1h, nullptr, 256, 256, 0, (b - 1024) * 256 + tid); return; }
    else if (b < 2000) {
        int idx = (b - 1280) * 256 + tid;
        if (idx < 256) zbias[idx] = 0.f;
        const float w0 = 2.f * PI_F / 128.f;
        float v;
        unsigned short *H, *L;
        int off;
        if (idx < 32768) {                     // Bf [256][128]
            int n = idx >> 7, k = idx & 127;
            int t = n & 127, r = (t * k) & 127;
            float s_, c_; sincosf(w0 * r, &s_, &c_);
            v = (n < 128) ? c_ : -s_;
            H = BfH; L = BfL; off = idx;
        } else if (idx < 98304) {              // Bfc [256][256]
            int i = idx - 32768;
            int n = i >> 8, j = i & 255;
            int t = n & 127, r = (t * (j & 127)) & 127;
            float s_, c_; sincosf(w0 * r, &s_, &c_);
            v = (n < 128) ? ((j < 128) ? c_ : s_) : ((j < 128) ? -s_ : c_);
            H = BfcH; L = BfcL; off = i;
        } else if (idx < 163840) {             // Bic [256][256]
            int i = idx - 98304;
            int n = i >> 8, j = i & 255;
            int t = n & 127, r = (t * (j & 127)) & 127;
            float s_, c_; sincosf(w0 * r, &s_, &c_);
            v = ((n < 128) ? ((j < 128) ? c_ : -s_) : ((j < 128) ? s_ : c_)) * (1.f / 128.f);
            H = BicH; L = BicL; off = i;
        } else if (idx < 184320) {             // Birf [160][128] fp32
            int i2 = idx - 163840;
            int col = i2 / 160, j = i2 - col * 160;
            if (j == 0) v = 1.f / 128.f;
            else if (j < 64)  { int r = (j * col) & 127; float s_, c_; sincosf(w0 * r, &s_, &c_); v = 2.f * c_ / 128.f; }
            else if (j == 64) v = (col & 1) ? -1.f / 128.f : 1.f / 128.f;
            else if (j >= 66 && j <= 128) { int k = j - 65; int r = (k * col) & 127; float s_, c_; sincosf(w0 * r, &s_, &c_); v = -2.f * s_ / 128.f; }
            else v = 0.f;
            Birf[j * 128 + col] = v;
            return;
        } else return;
        unsigned short hb = f2bf(v);
        H[off] = hb;
        L[off] = f2bf(v - bf2f(hb));
    }
    else if (b < 2016) {                       // d1ch compose
        float* E = smem;                       // [192]
        if (tid < 192) {
            int o = tid / 3, ci = tid - o * 3;
            float s = 0.f;
            #pragma unroll
            for (int r = 0; r < 8; r++) s += w_e2[o * 8 + r] * w_e1[r * 3 + ci];
            E[tid] = s;
        }
        __syncthreads();
        int idx = (b - 2000) * 256 + tid;      // < 4096
        int n = idx >> 5, k = idx & 31;
        float s = 0.f;
        if (k < 12) {
            int dydx = k / 3, ci = k - dydx * 3;
            #pragma unroll 16
            for (int o = 0; o < 64; o++) s += w_d1[n * 256 + o * 4 + dydx] * E[o * 3 + ci];
        }
        d1ch[idx] = f2bf(s);
    } else if (b == 2016) {                    // b1c fold
        float* f = smem;                       // [64]
        if (tid < 64) {
            int o = tid;
            float s = b_e2[o];
            #pragma unroll
            for (int r = 0; r < 8; r++) s += w_e2[o * 8 + r] * b_e1[r];
            f[o] = s;
        }
        __syncthreads();
        if (tid < 128) {
            float s = b_d1[tid];
            #pragma unroll 8
            for (int o = 0; o < 64; o++) {
                float fo = f[o];
                #pragma unroll
                for (int dydx = 0; dydx < 4; dydx++) s += w_d1[tid * 256 + o * 4 + dydx] * fo;
            }
            b1c[tid] = s;
        }
    } else if (b == 2017) {                    // Wc / W21c chain
        float* sWc = smem;                     // [384]
        float* sW2c = smem + 384;              // [384]
        if (tid < 128) {
            int j = tid;
            for (int r = 0; r < 3; r++) {
                float s = 0.f;
                #pragma unroll 16
                for (int o = 0; o < 64; o++) s += w3[r * 64 + o] * w2[o * 128 + j];
                sWc[r * 128 + j] = s;
                Wc[r * 128 + j] = s;
            }
            if (j < 3) {
                float s = b3[j];
                #pragma unroll 16
                for (int o = 0; o < 64; o++) s += w3[j * 64 + o] * b2[o];
                bc[j] = s;
            }
        }
        __syncthreads();
        if (tid < 128) {
            int j = tid;
            for (int r = 0; r < 3; r++) {
                float s = 0.f;
                #pragma unroll 16
                for (int o = 0; o < 64; o++) s += sWc[r * 128 + o] * wu2[o * 128 + j];
                sW2c[r * 128 + j] = s;
            }
        }
        __syncthreads();
        if (tid < 256) {
            int j = tid;
            for (int r = 0; r < 3; r++) {
                float s = 0.f;
                #pragma unroll 16
                for (int o = 0; o < 128; o++) s += sW2c[r * 128 + o] * wu1[o * 256 + j];
                W21c[r * 256 + j] = s;
            }
        }
        if (tid < 3) {
            float s = 0.f;
            #pragma unroll 16
            for (int o = 0; o < 128; o++) s += sW2c[tid * 128 + o] * bu1[o];
            #pragma unroll 16
            for (int o = 0; o < 64; o++)  s += sWc[tid * 128 + o] * bu2[o];
            b21c[tid] = s;
        }
    } else if (b < 2082) {                     // Wg / bgc (Uf row inline)
        int n = b - 2018;
        float* u = smem;                       // [256]
        float* red = smem + 256;               // [256]
        {
            float s = 0.f;
            #pragma unroll 16
            for (int o = 0; o < 128; o++) s += w_u4[n * 128 + o] * w_u3[o * 256 + tid];
            u[tid] = s;
        }
        __syncthreads();
        float s = 0.f;
        #pragma unroll 16
        for (int o = 0; o < 256; o++) s += u[o] * wsp2[o * 256 + tid];
        Wg[n * 256 + tid] = f2bf(s);
        float rv = u[tid] * bsp2[tid];
        if (tid < 128) rv += w_u4[n * 128 + tid] * b_u3[tid];
        red[tid] = rv;
        __syncthreads();
        for (int st = 128; st > 0; st >>= 1) {
            if (tid < st) red[tid] += red[tid + st];
            __syncthreads();
        }
        if (tid == 0) bgc[n] = b_u4[n] + red[0];
    } else {                                   // dark channel, i = b - 2082
        int i = b - 2082;
        float* rm = smem;                      // [15*512]
        float* cm = smem + 7680;               // [512]
        float* red = smem + 8192;              // [256]
        for (int idx = tid; idx < 15 * 512; idx += 256) {
            int rr = idx >> 9, j = idx & 511;
            int row = refl512(i - 7 + rr);
            int p = (row << 9) + j;
            rm[rr * 512 + j] = 1.0f - fmaxf(x[p], fmaxf(x[p + NPIX], x[p + 2 * NPIX]));
        }
        __syncthreads();
        #pragma unroll
        for (int h = 0; h < 2; h++) {
            int j = tid + h * 256;
            float m = 1e30f;
            #pragma unroll
            for (int rr = 0; rr < 15; rr++) m = fminf(m, rm[rr * 512 + j]);
            cm[j] = m;
        }
        __syncthreads();
        float best = -1e30f;
        #pragma unroll
        for (int h = 0; h < 2; h++) {
            int j = tid + h * 256;
            float m = 1e30f;
            #pragma unroll
            for (int d = -7; d <= 7; d++) m = fminf(m, cm[refl512(j + d)]);
            dark[(i << 9) + j] = m;
            best = fmaxf(best, m);
        }
        red[tid] = best;
        __syncthreads();
        for (int s = 128; s > 0; s >>= 1) {
            if (tid < s) red[tid] = fmaxf(red[tid], red[tid + s]);
            __syncthreads();
        }
        if (tid == 0) blockmax[i] = red[0];
    }
}

// ---------------------------------------------------------------- channels-first MFMA GEMM body (LDS passed in)
// MT: M-tile in units of 32 rows (4 -> 128-row tile, 2 -> 64-row tile).
// Wave-group row stride is MT*16 (each group covers MT tiles x 16 rows).
template<int AMODE, int SPLIT, int LRELU, int TSTORE, int ABF16, int CBF16, int MT>
__device__ __forceinline__ void mm_body(unsigned short* __restrict__ SH,
                                        const void* __restrict__ Asrc_,
                                        const unsigned short* __restrict__ Bh,
                                        const unsigned short* __restrict__ Bl,
                                        const float* __restrict__ bias, void* __restrict__ C_,
                                        int M, int N, int K, int cshift, int wshift, int srcW,
                                        int gy, int bid, int nwg) {
    const int ROWS = MT * 32;
    const int NHALF = MT / 2;                  // 2 for MT=4, 1 for MT=2
    const float* Af = (const float*)Asrc_;
    const unsigned short* A16 = (const unsigned short*)Asrc_;
    float* Cf = (float*)C_;
    unsigned short* C16 = (unsigned short*)C_;
    unsigned short* AhS = SH;                  // ROWS*40
    unsigned short* BhS = SH + ROWS * 40;      // 64*40
    unsigned short* AlS = SPLIT ? SH + ROWS * 40 + 2560 : SH;
    unsigned short* BlS = SPLIT ? SH + 2 * ROWS * 40 + 2560 : SH;
    int tid = threadIdx.x;
    int qq = nwg >> 3, rr = nwg & 7;
    int xcd = bid & 7, ixw = bid >> 3;
    int work = (xcd < rr) ? (xcd * (qq + 1) + ixw) : (rr * (qq + 1) + (xcd - rr) * qq + ixw);
    int bx = work / gy;
    int by = work - bx * gy;
    int m0 = bx * ROWS;
    int n0 = by * 64;
    int wave = tid >> 6, lane = tid & 63;
    int wm = (wave >> 1) * (MT * 16), wn = (wave & 1) * 32;   // group stride = MT*16
    int l15 = lane & 15, quad = lane >> 4;
    int lk = quad * 8, lk4 = quad * 4;
    fx4 acc[MT][2];
    #pragma unroll
    for (int a = 0; a < MT; a++)
        #pragma unroll
        for (int b = 0; b < 2; b++)
            acc[a][b] = (fx4){0.f, 0.f, 0.f, 0.f};

    int mm = tid & (ROWS - 1);
    int kpb = tid / ROWS;
    int gm = m0 + mm;
    int oj = 0, oi = 0, cA = 0, kfA = 0;
    size_t abase = 0;
    if (AMODE == 1) { oj = gm & ((1 << wshift) - 1); oi = gm >> wshift; }
    if (AMODE == 2) { oj = gm & 255; oi = gm >> 8; }
    if (AMODE == 3) abase = (size_t)gm * K;
    if (AMODE == 7) { cA = gm / 65; kfA = gm - cA * 65; }
    if (AMODE == 9) { cA = gm / 65; kfA = gm - cA * 65; }

    for (int kb = 0; kb < K; kb += 32) {
        if (AMODE == 3 && ABF16 && !SPLIT) {
            #pragma unroll
            for (int half = 0; half < NHALF; half++) {
                int off = (kpb * NHALF + half) * 8;
                sh8 hv = *(const sh8*)(const void*)&A16[abase + kb + off];
                *(sh8*)(void*)&AhS[mm * 40 + off] = hv;
            }
        } else {
            #pragma unroll
            for (int half = 0; half < NHALF; half++) {
                sh8 hv, lv;
                #pragma unroll
                for (int tt = 0; tt < 4; tt++) {
                    int kp = (kpb * NHALF + half) * 4 + tt;
                    int k0 = kb + kp * 2;
                    unsigned short h0, h1;
                    if (ABF16) {
                        size_t ad0, ad1;
                        if (AMODE == 0) {
                            ad0 = (size_t)k0 * M + gm;
                            ad1 = ad0 + M;
                        } else if (AMODE == 1) {
                            int c = k0 & ((1 << cshift) - 1);
                            int dydx = k0 >> cshift;
                            int dy = dydx >> 1, dx = dydx & 1;
                            size_t pix = (size_t)(2 * oi + dy) * srcW + (2 * oj + dx);
                            size_t plane = (size_t)srcW * srcW;
                            ad0 = (size_t)c * plane + pix;
                            ad1 = ad0 + plane;
                        } else if (AMODE == 3) {
                            ad0 = abase + k0;
                            ad1 = ad0 + 1;
                        } else {               // AMODE 7
                            int t0 = k0 & 127, hf = k0 >> 7;
                            ad0 = (size_t)(cA * 128 + t0) * 256 + hf * 128 + kfA;
                            ad1 = ad0 + 256;
                        }
                        h0 = A16[ad0];
                        h1 = A16[ad1];
                    } else {
                        float a0, a1;
                        if (AMODE == 2) {
                            if (k0 < 12) {
                                int d0 = k0 / 3, c0 = k0 - d0 * 3;
                                int k1 = k0 + 1;
                                int d1x = k1 / 3, c1 = k1 - d1x * 3;
                                a0 = Af[(size_t)c0 * NPIX + (size_t)(2 * oi + (d0 >> 1)) * 512 + 2 * oj + (d0 & 1)];
                                a1 = Af[(size_t)c1 * NPIX + (size_t)(2 * oi + (d1x >> 1)) * 512 + 2 * oj + (d1x & 1)];
                            } else { a0 = 0.f; a1 = 0.f; }
                        } else if (AMODE == 9) {
                            size_t ad = (size_t)cA * 16640 + (size_t)k0 * 65 + kfA;
                            float re0 = Af[ad], im0 = Af[ad + 2129920];
                            float re1 = Af[ad + 65], im1 = Af[ad + 65 + 2129920];
                            a0 = sqrtf(re0 * re0 + im0 * im0);
                            a1 = sqrtf(re1 * re1 + im1 * im1);
                        } else {
                            size_t ad0 = (size_t)k0 * M + gm;
                            a0 = Af[ad0];
                            a1 = Af[ad0 + M];
                        }
                        h0 = f2bf(a0);
                        h1 = f2bf(a1);
                        if (SPLIT) {
                            lv[tt * 2] = (short)f2bf(a0 - bf2f(h0));
                            lv[tt * 2 + 1] = (short)f2bf(a1 - bf2f(h1));
                        }
                    }
                    hv[tt * 2] = (short)h0;
                    hv[tt * 2 + 1] = (short)h1;
                }
                int coff = (kpb * NHALF + half) * 8;
                *(sh8*)(void*)&AhS[mm * 40 + coff] = hv;
                if (SPLIT) *(sh8*)(void*)&AlS[mm * 40 + coff] = lv;
            }
        }
        {
            int n = tid >> 2, seg = tid & 3;
            size_t gb = (size_t)(n0 + n) * K + kb + seg * 8;
            *(sh8*)(void*)&BhS[n * 40 + seg * 8] = *(const sh8*)(const void*)&Bh[gb];
            if (SPLIT) *(sh8*)(void*)&BlS[n * 40 + seg * 8] = *(const sh8*)(const void*)&Bl[gb];
        }
        __syncthreads();
        sh8 af[MT], bf[2], afl[MT], bfl[2];
        #pragma unroll
        for (int mt = 0; mt < MT; mt++) {
            af[mt] = *(const sh8*)(const void*)&AhS[(wm + mt * 16 + l15) * 40 + lk];
            if (SPLIT) afl[mt] = *(const sh8*)(const void*)&AlS[(wm + mt * 16 + l15) * 40 + lk];
        }
        #pragma unroll
        for (int nt = 0; nt < 2; nt++) {
            bf[nt] = *(const sh8*)(const void*)&BhS[(wn + nt * 16 + l15) * 40 + lk];
            if (SPLIT) bfl[nt] = *(const sh8*)(const void*)&BlS[(wn + nt * 16 + l15) * 40 + lk];
        }
        #pragma unroll
        for (int mt = 0; mt < MT; mt++)
            #pragma unroll
            for (int nt = 0; nt < 2; nt++) {
                acc[mt][nt] = __builtin_amdgcn_mfma_f32_16x16x32_bf16(af[mt], bf[nt], acc[mt][nt], 0, 0, 0);
                if (SPLIT) {
                    acc[mt][nt] = __builtin_amdgcn_mfma_f32_16x16x32_bf16(af[mt], bfl[nt], acc[mt][nt], 0, 0, 0);
                    acc[mt][nt] = __builtin_amdgcn_mfma_f32_16x16x32_bf16(afl[mt], bf[nt], acc[mt][nt], 0, 0, 0);
                }
            }
        __syncthreads();
    }
    #pragma unroll
    for (int nt = 0; nt < 2; nt++) {
        int n = n0 + wn + nt * 16 + l15;
        float bs = bias[n];
        #pragma unroll
        for (int mt = 0; mt < MT; mt++) {
            int mbase = m0 + wm + mt * 16 + lk4;
            if (TSTORE) {
                #pragma unroll
                for (int r = 0; r < 4; r++) {
                    float q = acc[mt][nt][r] + bs;
                    if (LRELU) q = (q < 0.f) ? 0.1f * q : q;
                    if (CBF16) C16[(size_t)(mbase + r) * N + n] = f2bf(q);
                    else       Cf[(size_t)(mbase + r) * N + n] = q;
                }
            } else if (CBF16) {
                ush4 v;
                #pragma unroll
                for (int r = 0; r < 4; r++) {
                    float q = acc[mt][nt][r] + bs;
                    if (LRELU) q = (q < 0.f) ? 0.1f * q : q;
                    v[r] = f2bf(q);
                }
                *(ush4*)(void*)&C16[(size_t)n * M + mbase] = v;
            } else {
                float4 v;
                float* vp = (float*)&v;
                #pragma unroll
                for (int r = 0; r < 4; r++) {
                    float q = acc[mt][nt][r] + bs;
                    if (LRELU) q = (q < 0.f) ? 0.1f * q : q;
                    vp[r] = q;
                }
                *(float4*)&Cf[(size_t)n * M + mbase] = v;
            }
        }
    }
}

// single-GEMM wrapper
template<int AMODE, int SPLIT, int LRELU, int TSTORE, int ABF16, int CBF16, int MT>
__global__ __launch_bounds__(256) void k_mmcf(const void* __restrict__ Asrc_,
                                              const unsigned short* __restrict__ Bh,
                                              const unsigned short* __restrict__ Bl,
                                              const float* __restrict__ bias, void* __restrict__ C_,
                                              int M, int N, int K, int cshift, int wshift, int srcW,
                                              int gy) {
    __shared__ unsigned short SH[SPLIT ? (2 * MT * 32 * 40 + 5120) : (MT * 32 * 40 + 2560)];
    mm_body<AMODE, SPLIT, LRELU, TSTORE, ABF16, CBF16, MT>(SH, Asrc_, Bh, Bl, bias, C_,
                                                           M, N, K, cshift, wshift, srcW, gy,
                                                           (int)blockIdx.x, (int)gridDim.x);
}

// d1 GEMM + 1 extra block reducing blockmax -> gmax
__global__ __launch_bounds__(256) void k_d1(const float* __restrict__ x,
                                            const unsigned short* __restrict__ d1ch,
                                            const float* __restrict__ b1c, unsigned short* __restrict__ xd1,
                                            const float* __restrict__ blockmax, int* __restrict__ gmax) {
    if (blockIdx.x == 1024) {
        __shared__ float red[256];
        int tid = threadIdx.x;
        red[tid] = fmaxf(blockmax[tid], blockmax[tid + 256]);
        __syncthreads();
        for (int s = 128; s > 0; s >>= 1) {
            if (tid < s) red[tid] = fmaxf(red[tid], red[tid + s]);
            __syncthreads();
        }
        if (tid == 0) gmax[0] = __float_as_int(red[0]);
        return;
    }
    __shared__ unsigned short SH[7680];
    mm_body<2, 0, 0, 0, 0, 1, 4>(SH, x, d1ch, nullptr, b1c, xd1, 65536, 128, 32, 0, 0, 0, 2,
                                 (int)blockIdx.x, 1024);
}

// F1 (1024 blocks) || sp1 (512 blocks)
__global__ __launch_bounds__(256) void k_dualA(const unsigned short* __restrict__ xd2,
                                               const unsigned short* __restrict__ BfH,
                                               const float* __restrict__ zbias, unsigned short* __restrict__ F1T,
                                               const unsigned short* __restrict__ s1h,
                                               const float* __restrict__ b_sp1, unsigned short* __restrict__ s1) {
    __shared__ unsigned short SH[7680];
    if (blockIdx.x < 1024)
        mm_body<3, 0, 0, 1, 1, 1, 4>(SH, xd2, BfH, nullptr, zbias, F1T, 32768, 256, 128, 0, 0, 0, 4,
                                     (int)blockIdx.x, 1024);
    else
        mm_body<0, 0, 1, 0, 1, 1, 4>(SH, xd2, s1h, nullptr, b_sp1, s1, 16384, 256, 256, 0, 0, 0, 4,
                                     (int)blockIdx.x - 1024, 512);
}

// F2 at MT=2 (1040 blocks) || g4s (128 blocks)
__global__ __launch_bounds__(256) void k_dualB(const unsigned short* __restrict__ F1T,
                                               const unsigned short* __restrict__ BfcH,
                                               const float* __restrict__ zbias, float* __restrict__ F2C,
                                               const unsigned short* __restrict__ s1,
                                               const unsigned short* __restrict__ Wg,
                                               const float* __restrict__ bgc, float* __restrict__ g4s) {
    __shared__ unsigned short SH[7680];
    if (blockIdx.x < 1040)
        mm_body<7, 0, 0, 0, 1, 0, 2>(SH, F1T, BfcH, nullptr, zbias, F2C, 16640, 256, 256, 0, 0, 0, 4,
                                     (int)blockIdx.x, 1040);
    else
        mm_body<0, 0, 0, 0, 1, 0, 4>(SH, s1, Wg, nullptr, bgc, g4s, 16384, 64, 256, 0, 0, 0, 1,
                                     (int)blockIdx.x - 1040, 128);
}

// ---------------------------------------------------------------- z = a*(cos a, sin a), flattened full-wave, bf16
__global__ __launch_bounds__(256) void k_zbuild(const float* __restrict__ A2, unsigned short* __restrict__ Z) {
    int idx = blockIdx.x * 256 + threadIdx.x;   // < 2129920
    int ct = idx / 65, kf = idx - ct * 65;
    int c = ct >> 7, t = ct & 127;
    float a = A2[idx];
    float s_, c_;
    sincosf(a, &s_, &c_);
    size_t m = (size_t)c * 65 + kf;
    Z[(size_t)t * 16640 + m] = f2bf(a * c_);
    Z[2129920 + (size_t)t * 16640 + m] = f2bf(a * s_);
}

// ---------------------------------------------------------------- P[r][kf][ht] = sum_c W21c[r][c] * I1T[(c,kf)][ht]  (coalesced in ht)
__global__ __launch_bounds__(256) void k_pfold(const unsigned short* __restrict__ I1T,
                                               const float* __restrict__ W21c, float* __restrict__ P) {
    __shared__ float wa[768];
    int kf = blockIdx.x, tid = threadIdx.x;
    for (int t = tid; t < 768; t += 256) wa[t] = W21c[t];
    __syncthreads();
    float a0 = 0.f, a1 = 0.f, a2 = 0.f;
    #pragma unroll 4
    for (int c = 0; c < 256; c++) {
        float v = bf2f(I1T[(size_t)(c * 65 + kf) * 256 + tid]);
        a0 += wa[c] * v;
        a1 += wa[256 + c] * v;
        a2 += wa[512 + c] * v;
    }
    P[(size_t)(0 * 65 + kf) * 256 + tid] = a0;
    P[(size_t)(1 * 65 + kf) * 256 + tid] = a1;
    P[(size_t)(2 * 65 + kf) * 256 + tid] = a2;
}

// ---------------------------------------------------------------- h3s[r][tau][col] = sum_k Birf[k][col] * P[r][kf(k)][hf(k),tau] + b21c[r]
__global__ __launch_bounds__(128) void k_h3f(const float* __restrict__ P, const float* __restrict__ Birf,
                                             const float* __restrict__ b21c, float* __restrict__ h3s) {
    __shared__ float sp[390];
    __shared__ float bs[3];
    int tau = blockIdx.x, col = threadIdx.x;
    for (int t = col; t < 390; t += 128) {
        int r = t / 130, rem = t - r * 130;
        int hf = rem / 65, kf = rem - hf * 65;
        sp[t] = P[(size_t)(r * 65 + kf) * 256 + hf * 128 + tau];
    }
    if (col < 3) bs[col] = b21c[col];
    __syncthreads();
    float f0 = 0.f, f1 = 0.f, f2 = 0.f;
    for (int k0 = 0; k0 < 130; k0++) {
        float w = Birf[k0 * 128 + col];
        f0 += w * sp[k0];
        f1 += w * sp[130 + k0];
        f2 += w * sp[260 + k0];
    }
    size_t q = (size_t)tau * 128 + col;
    h3s[q]         = f0 + bs[0];
    h3s[16384 + q] = f1 + bs[1];
    h3s[32768 + q] = f2 + bs[2];
}

// ---------------------------------------------------------------- final fused stage @512^2 (y-interp staged in LDS)
__global__ __launch_bounds__(256) void k_final(const float* __restrict__ x,
                                               const float* __restrict__ dark, const int* __restrict__ gmax,
                                               const float* __restrict__ wcf1, const float* __restrict__ bcf1,
                                               const float* __restrict__ Wc, const float* __restrict__ bc,
                                               const float* __restrict__ g4s, const float* __restrict__ h3s,
                                               float* __restrict__ out) {
    __shared__ float idimt[32], w1[192], b1[64], wb[192], bcs[3], posy[16];
    __shared__ float gyr[64][68];
    __shared__ float hyr[3][68];
    int tid = threadIdx.x;
    int bid = blockIdx.x;
    int i = bid >> 1;
    int j0 = (bid & 1) << 8;
    int j = j0 + tid;
    int p = (i << 9) + j;

    const float scale = 2.f * PI_F;
    float inv511 = scale / (511.f + 1e-6f);
    float ye = (float)i * inv511;

    if (tid < 32) idimt[tid] = 1.f / powf(10000.f, (float)(2 * (tid >> 1)) / 32.f);
    if (tid < 192) w1[tid] = wcf1[tid];
    if (tid < 64) b1[tid] = bcf1[tid];
    if (tid < 192) { int r = tid / 64, c = tid - (tid / 64) * 64; wb[tid] = Wc[r * 128 + 64 + c]; }
    if (tid < 3) bcs[tid] = bc[tid];
    __syncthreads();
    if (tid >= 32 && tid < 48) {
        int c = tid - 32;
        float e = ye * idimt[c];
        posy[c] = ((c & 1) == 0) ? __sinf(e) : __cosf(e);
    }

    int ky = i >> 2, ry = i & 3;
    int ym = (ky > 0) ? ky - 1 : 0, yp = (ky < 127) ? ky + 1 : 127;
    float wy0 = (ry == 0) ? .375f : (ry == 1) ? .1875f : (ry == 2) ? .0625f : 0.f;
    float wy1 = (ry == 0 || ry == 3) ? .625f : .75f;
    float wy2 = (ry == 0) ? 0.f : (ry == 1) ? .0625f : (ry == 2) ? .1875f : .375f;
    int base = j0 >> 2;
    int r0 = ym * 128, r1 = ky * 128, r2 = yp * 128;
    for (int idx = tid; idx < 64 * 66; idx += 256) {
        int c = idx / 66, t = idx - c * 66;
        int col = base - 1 + t;
        col = (col < 0) ? 0 : (col > 127) ? 127 : col;
        const float* gp = g4s + (size_t)c * 16384;
        gyr[c][t] = wy0 * gp[r0 + col] + wy1 * gp[r1 + col] + wy2 * gp[r2 + col];
    }
    for (int idx = tid; idx < 3 * 66; idx += 256) {
        int c = idx / 66, t = idx - c * 66;
        int col = base - 1 + t;
        col = (col < 0) ? 0 : (col > 127) ? 127 : col;
        const float* hp = h3s + (size_t)c * 16384;
        hyr[c][t] = wy0 * hp[r0 + col] + wy1 * hp[r1 + col] + wy2 * hp[r2 + col];
    }
    __syncthreads();

    float xe = (float)j * inv511;
    float gm = __int_as_float(gmax[0]);
    float ze = dark[p] / (gm + 1e-6f) * scale;
    float x0 = x[p], x1 = x[p + NPIX], x2 = x[p + 2 * NPIX];

    int rx = j & 3;
    int tx = tid >> 2;
    float wx0 = (rx == 0) ? .375f : (rx == 1) ? .1875f : (rx == 2) ? .0625f : 0.f;
    float wx1 = (rx == 0 || rx == 3) ? .625f : .75f;
    float wx2 = (rx == 0) ? 0.f : (rx == 1) ? .0625f : (rx == 2) ? .1875f : .375f;

    float a0 = 0.f, a1 = 0.f, a2 = 0.f;
    #pragma unroll 1
    for (int c = 0; c < 64; c++) {
        float pos;
        if (c < 16)      { float e = xe * idimt[c];      pos = ((c & 1) == 0) ? __sinf(e) : __cosf(e); }
        else if (c < 32) { pos = posy[c - 16]; }
        else             { float e = ze * idimt[c - 32]; pos = ((c & 1) == 0) ? __sinf(e) : __cosf(e); }
        float ape = pos + w1[c * 3] * x0 + w1[c * 3 + 1] * x1 + w1[c * 3 + 2] * x2 + b1[c];
        float gv = wx0 * gyr[c][tx] + wx1 * gyr[c][tx + 1] + wx2 * gyr[c][tx + 2];
        float s = gv * ape;
        a0 += wb[c] * s; a1 += wb[64 + c] * s; a2 += wb[128 + c] * s;
    }
    float f0 = wx0 * hyr[0][tx] + wx1 * hyr[0][tx + 1] + wx2 * hyr[0][tx + 2];
    float f1 = wx0 * hyr[1][tx] + wx1 * hyr[1][tx + 1] + wx2 * hyr[1][tx + 2];
    float f2 = wx0 * hyr[2][tx] + wx1 * hyr[2][tx + 1] + wx2 * hyr[2][tx + 2];
    out[p]            = a0 + f0 + bcs[0] + x0;
    out[NPIX + p]     = a1 + f1 + bcs[1] + x1;
    out[2 * NPIX + p] = a2 + f2 + bcs[2] + x2;
}

// ================================================================ launcher
extern "C" void kernel_launch(void* const* d_in, const int* in_sizes, int n_in,
                              void* d_out, int out_size, void* d_ws, size_t ws_size,
                              hipStream_t stream) {
    const float* x      = (const float*)d_in[0];
    const float* w_cf1  = (const float*)d_in[1];  const float* b_cf1 = (const float*)d_in[2];
    const float* w_e1   = (const float*)d_in[3];  const float* b_e1  = (const float*)d_in[4];
    const float* w_e2   = (const float*)d_in[5];  const float* b_e2  = (const float*)d_in[6];
    const float* w_d1   = (const float*)d_in[7];  const float* b_d1  = (const float*)d_in[8];
    const float* w_d2   = (const float*)d_in[9];  const float* b_d2  = (const float*)d_in[10];
    // 11..14: pha branch is dead code in the reference
    const float* w_amp1 = (const float*)d_in[15]; const float* b_amp1 = (const float*)d_in[16];
    const float* w_amp2 = (const float*)d_in[17]; const float* b_amp2 = (const float*)d_in[18];
    const float* w_sp1  = (const float*)d_in[19]; const float* b_sp1  = (const float*)d_in[20];
    const float* w_sp2  = (const float*)d_in[21]; const float* b_sp2  = (const float*)d_in[22];
    const float* w_u1   = (const float*)d_in[23]; const float* b_u1   = (const float*)d_in[24];
    const float* w_u2   = (const float*)d_in[25]; const float* b_u2   = (const float*)d_in[26];
    const float* w_u3   = (const float*)d_in[27]; const float* b_u3   = (const float*)d_in[28];
    const float* w_u4   = (const float*)d_in[29]; const float* b_u4   = (const float*)d_in[30];
    const float* w_cf2  = (const float*)d_in[31]; const float* b_cf2  = (const float*)d_in[32];
    const float* w_cf3  = (const float*)d_in[33]; const float* b_cf3  = (const float*)d_in[34];
    float* out = (float*)d_out;

    char* ws = (char*)d_ws;
    constexpr size_t MiB = 1ull << 20;
    float*  dark   = (float*)(ws + 0 * MiB);
    int*    gmax   = (int*)  (ws + 2 * MiB);
    float*  Wc     = (float*)(ws + 2 * MiB + 1024);
    float*  bc     = (float*)(ws + 2 * MiB + 2560);
    float*  W21c   = (float*)(ws + 2 * MiB + 4096);
    float*  b21c   = (float*)(ws + 2 * MiB + 7168);
    float*  blockmax = (float*)(ws + 2 * MiB + 8192);             // [512]
    unsigned short* d1ch = (unsigned short*)(ws + 3 * MiB);       // bf16 [128][32]
    float*  b1c    = (float*)(ws + 3 * MiB + 16384);
    unsigned short* Wg = (unsigned short*)(ws + 3 * MiB + 131072);// bf16 [64][256]
    float*  bgc    = (float*)(ws + 3 * MiB + 196608);
    unsigned short* xd1 = (unsigned short*)(ws + 67 * MiB);   // bf16 [128][65536] = 16 MiB
    unsigned short* xd2 = (unsigned short*)(ws + 99 * MiB);   // bf16 [256][16384] =  8 MiB
    unsigned short* F1T = (unsigned short*)(ws + 115 * MiB);  // bf16 [32768][256] = 16 MiB
    float*  F2C    = (float*)(ws + 147 * MiB);                // fp32 (feeds sqrt fused in amp1)
    float*  A1     = (float*)(ws + 173 * MiB);
    float*  A2     = (float*)(ws + 182 * MiB);
    unsigned short* Zbuf = (unsigned short*)(ws + 115 * MiB); // bf16 (F1T dead after F2)
    unsigned short* I1T  = (unsigned short*)(ws + 132 * MiB); // bf16 [16640][256] = 8.5 MiB
    float*  P      = (float*)(ws + 149 * MiB);                // fp32 [3][65][256]
    float*  h3s    = (float*)(ws + 11 * MiB);                 // fp32 [3][16384]
    unsigned short* s1 = (unsigned short*)(ws + 31 * MiB);    // bf16 [256][16384] = 8 MiB
    float*  g4s    = (float*)(ws + 87 * MiB);                 // fp32 [64][16384]
    unsigned short* wb16 = (unsigned short*)(ws + 192 * MiB);
    unsigned short* d2h = wb16 + 65536,   * d2l = wb16 + 196608;
    unsigned short* a1h = wb16 + 327680,  * a1l = wb16 + 393216;
    unsigned short* a2h = wb16 + 458752,  * a2l = wb16 + 524288;
    unsigned short* s1h = wb16 + 589824;
    unsigned short* BfH = wb16 + 786432,  * BfL = wb16 + 819200;
    unsigned short* BfcH = wb16 + 851968, * BfcL = wb16 + 917504;
    unsigned short* BicH = wb16 + 983040, * BicL = wb16 + 1048576;
    float* zbias = (float*)(ws + 195 * MiB + 512 * 1024);
    float* Birf  = (float*)(ws + 196 * MiB);                  // fp32 [160][128]

    // 1) mega prep: weights + tables + composes + dark (one launch)
    k_prep<<<2594, 256, 0, stream>>>(
        x, dark, blockmax,
        w_d2, d2h, d2l, w_amp1, a1h, a1l, w_amp2, a2h, a2l, w_sp1, s1h,
        BfH, BfL, BfcH, BfcL, BicH, BicL, Birf, zbias,
        w_e1, b_e1, w_e2, b_e2, w_d1, b_d1, d1ch, b1c,
        w_u3, w_u4, b_u3, b_u4, w_sp2, b_sp2, Wg, bgc,
        w_cf2, b_cf2, w_cf3, b_cf3, w_u2, b_u2, w_u1, b_u1,
        Wc, bc, W21c, b21c);

    // 2) d1 (+ gmax reduce rides along) ; d2 at MT=2 (1024 blocks, 4 blocks/CU)
    k_d1<<<1025, 256, 0, stream>>>(x, d1ch, b1c, xd1, blockmax, gmax);
    k_mmcf<1, 0, 0, 0, 1, 1, 2><<<1024, 256, 0, stream>>>(xd1, d2h, nullptr, b_d2, xd2, 16384, 256, 512, 7, 7, 256, 4);

    // 3) F1 || sp1 ; F2 (MT=2) || g4s
    k_dualA<<<1536, 256, 0, stream>>>(xd2, BfH, zbias, F1T, s1h, b_sp1, s1);
    k_dualB<<<1168, 256, 0, stream>>>(F1T, BfcH, zbias, F2C, s1, Wg, bgc, g4s);

    // 4) amp MLP at MT=2 ; zbuild ; I1 at MT=2 (1040 blocks)
    k_mmcf<9, 1, 1, 0, 0, 0, 2><<<520, 256, 0, stream>>>(F2C, a1h, a1l, b_amp1, A1, 8320, 256, 256, 0, 0, 0, 4);
    k_mmcf<0, 1, 0, 0, 0, 0, 2><<<520, 256, 0, stream>>>(A1, a2h, a2l, b_amp2, A2, 8320, 256, 256, 0, 0, 0, 4);
    k_zbuild<<<8320, 256, 0, stream>>>(A2, Zbuf);
    k_mmcf<0, 0, 0, 1, 1, 1, 2><<<1040, 256, 0, stream>>>(Zbuf, BicH, nullptr, zbias, I1T, 16640, 256, 256, 0, 0, 0, 4);

    // 5) factored h3: P = W21c ∘ I1T (coalesced) ; h3s = Birf ∘ P
    k_pfold<<<65, 256, 0, stream>>>(I1T, W21c, P);
    k_h3f<<<128, 128, 0, stream>>>(P, Birf, b21c, h3s);

    // 6) final fused stage
    k_final<<<1024, 256, 0, stream>>>(x, dark, gmax, w_cf1, b_cf1, Wc, bc, g4s, h3s, out);
}

// Round 16
// 300.747 us; speedup vs baseline: 1.0105x; 1.0105x over previous
//
#include <hip/hip_runtime.h>
#include <math.h>

#define PI_F 3.14159265358979323846f
#define NPIX 262144   // 512*512

typedef __attribute__((ext_vector_type(8))) short sh8;
typedef __attribute__((ext_vector_type(4))) float fx4;
typedef __attribute__((ext_vector_type(4))) unsigned short ush4;

__device__ __forceinline__ unsigned short f2bf(float v) {
    unsigned u = __float_as_uint(v);
    return (unsigned short)((u + 0x7FFFu + ((u >> 16) & 1)) >> 16);
}
__device__ __forceinline__ float bf2f(unsigned short h) {
    return __uint_as_float((unsigned)h << 16);
}

__device__ __forceinline__ int refl512(int t) {
    if (t < 0) t = -t;
    if (t > 511) t = 1022 - t;
    return t;
}

// ---------------------------------------------------------------- prep helpers (device)
__device__ __forceinline__ void prep_one(const float* __restrict__ w, unsigned short* __restrict__ h,
                                         unsigned short* __restrict__ l, int N, int K, int cshift, int idx) {
    if (idx >= N * K) return;
    int n = idx / K, kord = idx - n * K;
    int ksrc = kord;
    if (cshift) {
        int dydx = kord >> cshift, c = kord & ((1 << cshift) - 1);
        ksrc = c * 4 + dydx;
    }
    float v = w[n * K + ksrc];
    unsigned short hb = f2bf(v);
    h[idx] = hb;
    if (l) l[idx] = f2bf(v - bf2f(hb));
}

// ---------------------------------------------------------------- MEGA prep: weights + DFT tables + composes + dark channel
__global__ __launch_bounds__(256) void k_prep(
    const float* __restrict__ x, float* __restrict__ dark, float* __restrict__ blockmax,
    const float* __restrict__ w_d2, unsigned short* __restrict__ d2h, unsigned short* __restrict__ d2l,
    const float* __restrict__ w_a1, unsigned short* __restrict__ a1h, unsigned short* __restrict__ a1l,
    const float* __restrict__ w_a2, unsigned short* __restrict__ a2h, unsigned short* __restrict__ a2l,
    const float* __restrict__ w_s1, unsigned short* __restrict__ s1h,
    unsigned short* __restrict__ BfH, unsigned short* __restrict__ BfL,
    unsigned short* __restrict__ BfcH, unsigned short* __restrict__ BfcL,
    unsigned short* __restrict__ BicH, unsigned short* __restrict__ BicL,
    float* __restrict__ Birf, float* __restrict__ zbias,
    const float* __restrict__ w_e1, const float* __restrict__ b_e1,
    const float* __restrict__ w_e2, const float* __restrict__ b_e2,
    const float* __restrict__ w_d1, const float* __restrict__ b_d1,
    unsigned short* __restrict__ d1ch, float* __restrict__ b1c,
    const float* __restrict__ w_u3, const float* __restrict__ w_u4,
    const float* __restrict__ b_u3, const float* __restrict__ b_u4,
    const float* __restrict__ wsp2, const float* __restrict__ bsp2,
    unsigned short* __restrict__ Wg, float* __restrict__ bgc,
    const float* __restrict__ w2, const float* __restrict__ b2,
    const float* __restrict__ w3, const float* __restrict__ b3,
    const float* __restrict__ wu2, const float* __restrict__ bu2,
    const float* __restrict__ wu1, const float* __restrict__ bu1,
    float* __restrict__ Wc, float* __restrict__ bc,
    float* __restrict__ W21c, float* __restrict__ b21c) {
    __shared__ float smem[8448];   // rm[7680] | cm[512] | red[256] (branch-aliased)
    int b = blockIdx.x, tid = threadIdx.x;
    if (b < 512)       { prep_one(w_d2, d2h, d2l, 256, 512, 7, b * 256 + tid); return; }
    else if (b < 768)  { prep_one(w_a1, a1h, a1l, 256, 256, 0, (b - 512) * 256 + tid); return; }
    else if (b < 1024) { prep_one(w_a2, a2h, a2l, 256, 256, 0, (b - 768) * 256 + tid); return; }
    else if (b < 1280) { prep_one(w_s1, s1h, nullptr, 256, 256, 0, (b - 1024) * 256 + tid); return; }
    else if (b < 2000) {
        int idx = (b - 1280) * 256 + tid;
        if (idx < 256) zbias[idx] = 0.f;
        const float w0 = 2.f * PI_F / 128.f;
        float v;
        unsigned short *H, *L;
        int off;
        if (idx < 32768) {                     // Bf [256][128]
            int n = idx >> 7, k = idx & 127;
            int t = n & 127, r = (t * k) & 127;
            float s_, c_; sincosf(w0 * r, &s_, &c_);
            v = (n < 128) ? c_ : -s_;
            H = BfH; L = BfL; off = idx;
        } else if (idx < 98304) {              // Bfc [256][256]
            int i = idx - 32768;
            int n = i >> 8, j = i & 255;
            int t = n & 127, r = (t * (j & 127)) & 127;
            float s_, c_; sincosf(w0 * r, &s_, &c_);
            v = (n < 128) ? ((j < 128) ? c_ : s_) : ((j < 128) ? -s_ : c_);
            H = BfcH; L = BfcL; off = i;
        } else if (idx < 163840) {             // Bic [256][256]
            int i = idx - 98304;
            int n = i >> 8, j = i & 255;
            int t = n & 127, r = (t * (j & 127)) & 127;
            float s_, c_; sincosf(w0 * r, &s_, &c_);
            v = ((n < 128) ? ((j < 128) ? c_ : -s_) : ((j < 128) ? s_ : c_)) * (1.f / 128.f);
            H = BicH; L = BicL; off = i;
        } else if (idx < 184320) {             // Birf [160][128] fp32
            int i2 = idx - 163840;
            int col = i2 / 160, j = i2 - col * 160;
            if (j == 0) v = 1.f / 128.f;
            else if (j < 64)  { int r = (j * col) & 127; float s_, c_; sincosf(w0 * r, &s_, &c_); v = 2.f * c_ / 128.f; }
            else if (j == 64) v = (col & 1) ? -1.f / 128.f : 1.f / 128.f;
            else if (j >= 66 && j <= 128) { int k = j - 65; int r = (k * col) & 127; float s_, c_; sincosf(w0 * r, &s_, &c_); v = -2.f * s_ / 128.f; }
            else v = 0.f;
            Birf[j * 128 + col] = v;
            return;
        } else return;
        unsigned short hb = f2bf(v);
        H[off] = hb;
        L[off] = f2bf(v - bf2f(hb));
    }
    else if (b < 2016) {                       // d1ch compose
        float* E = smem;                       // [192]
        if (tid < 192) {
            int o = tid / 3, ci = tid - o * 3;
            float s = 0.f;
            #pragma unroll
            for (int r = 0; r < 8; r++) s += w_e2[o * 8 + r] * w_e1[r * 3 + ci];
            E[tid] = s;
        }
        __syncthreads();
        int idx = (b - 2000) * 256 + tid;      // < 4096
        int n = idx >> 5, k = idx & 31;
        float s = 0.f;
        if (k < 12) {
            int dydx = k / 3, ci = k - dydx * 3;
            #pragma unroll 16
            for (int o = 0; o < 64; o++) s += w_d1[n * 256 + o * 4 + dydx] * E[o * 3 + ci];
        }
        d1ch[idx] = f2bf(s);
    } else if (b == 2016) {                    // b1c fold
        float* f = smem;                       // [64]
        if (tid < 64) {
            int o = tid;
            float s = b_e2[o];
            #pragma unroll
            for (int r = 0; r < 8; r++) s += w_e2[o * 8 + r] * b_e1[r];
            f[o] = s;
        }
        __syncthreads();
        if (tid < 128) {
            float s = b_d1[tid];
            #pragma unroll 8
            for (int o = 0; o < 64; o++) {
                float fo = f[o];
                #pragma unroll
                for (int dydx = 0; dydx < 4; dydx++) s += w_d1[tid * 256 + o * 4 + dydx] * fo;
            }
            b1c[tid] = s;
        }
    } else if (b == 2017) {                    // Wc / W21c chain
        float* sWc = smem;                     // [384]
        float* sW2c = smem + 384;              // [384]
        if (tid < 128) {
            int j = tid;
            for (int r = 0; r < 3; r++) {
                float s = 0.f;
                #pragma unroll 16
                for (int o = 0; o < 64; o++) s += w3[r * 64 + o] * w2[o * 128 + j];
                sWc[r * 128 + j] = s;
                Wc[r * 128 + j] = s;
            }
            if (j < 3) {
                float s = b3[j];
                #pragma unroll 16
                for (int o = 0; o < 64; o++) s += w3[j * 64 + o] * b2[o];
                bc[j] = s;
            }
        }
        __syncthreads();
        if (tid < 128) {
            int j = tid;
            for (int r = 0; r < 3; r++) {
                float s = 0.f;
                #pragma unroll 16
                for (int o = 0; o < 64; o++) s += sWc[r * 128 + o] * wu2[o * 128 + j];
                sW2c[r * 128 + j] = s;
            }
        }
        __syncthreads();
        if (tid < 256) {
            int j = tid;
            for (int r = 0; r < 3; r++) {
                float s = 0.f;
                #pragma unroll 16
                for (int o = 0; o < 128; o++) s += sW2c[r * 128 + o] * wu1[o * 256 + j];
                W21c[r * 256 + j] = s;
            }
        }
        if (tid < 3) {
            float s = 0.f;
            #pragma unroll 16
            for (int o = 0; o < 128; o++) s += sW2c[tid * 128 + o] * bu1[o];
            #pragma unroll 16
            for (int o = 0; o < 64; o++)  s += sWc[tid * 128 + o] * bu2[o];
            b21c[tid] = s;
        }
    } else if (b < 2082) {                     // Wg / bgc (Uf row inline)
        int n = b - 2018;
        float* u = smem;                       // [256]
        float* red = smem + 256;               // [256]
        {
            float s = 0.f;
            #pragma unroll 16
            for (int o = 0; o < 128; o++) s += w_u4[n * 128 + o] * w_u3[o * 256 + tid];
            u[tid] = s;
        }
        __syncthreads();
        float s = 0.f;
        #pragma unroll 16
        for (int o = 0; o < 256; o++) s += u[o] * wsp2[o * 256 + tid];
        Wg[n * 256 + tid] = f2bf(s);
        float rv = u[tid] * bsp2[tid];
        if (tid < 128) rv += w_u4[n * 128 + tid] * b_u3[tid];
        red[tid] = rv;
        __syncthreads();
        for (int st = 128; st > 0; st >>= 1) {
            if (tid < st) red[tid] += red[tid + st];
            __syncthreads();
        }
        if (tid == 0) bgc[n] = b_u4[n] + red[0];
    } else {                                   // dark channel, i = b - 2082
        int i = b - 2082;
        float* rm = smem;                      // [15*512]
        float* cm = smem + 7680;               // [512]
        float* red = smem + 8192;              // [256]
        for (int idx = tid; idx < 15 * 512; idx += 256) {
            int rr = idx >> 9, j = idx & 511;
            int row = refl512(i - 7 + rr);
            int p = (row << 9) + j;
            rm[rr * 512 + j] = 1.0f - fmaxf(x[p], fmaxf(x[p + NPIX], x[p + 2 * NPIX]));
        }
        __syncthreads();
        #pragma unroll
        for (int h = 0; h < 2; h++) {
            int j = tid + h * 256;
            float m = 1e30f;
            #pragma unroll
            for (int rr = 0; rr < 15; rr++) m = fminf(m, rm[rr * 512 + j]);
            cm[j] = m;
        }
        __syncthreads();
        float best = -1e30f;
        #pragma unroll
        for (int h = 0; h < 2; h++) {
            int j = tid + h * 256;
            float m = 1e30f;
            #pragma unroll
            for (int d = -7; d <= 7; d++) m = fminf(m, cm[refl512(j + d)]);
            dark[(i << 9) + j] = m;
            best = fmaxf(best, m);
        }
        red[tid] = best;
        __syncthreads();
        for (int s = 128; s > 0; s >>= 1) {
            if (tid < s) red[tid] = fmaxf(red[tid], red[tid + s]);
            __syncthreads();
        }
        if (tid == 0) blockmax[i] = red[0];
    }
}

// ---------------------------------------------------------------- channels-first MFMA GEMM body (LDS passed in)
// MT: M-tile in units of 32 rows (4 -> 128-row tile, 2 -> 64-row tile).
// Wave-group row stride is MT*16 (each group covers MT tiles x 16 rows).
template<int AMODE, int SPLIT, int LRELU, int TSTORE, int ABF16, int CBF16, int MT>
__device__ __forceinline__ void mm_body(unsigned short* __restrict__ SH,
                                        const void* __restrict__ Asrc_,
                                        const unsigned short* __restrict__ Bh,
                                        const unsigned short* __restrict__ Bl,
                                        const float* __restrict__ bias, void* __restrict__ C_,
                                        int M, int N, int K, int cshift, int wshift, int srcW,
                                        int gy, int bid, int nwg) {
    const int ROWS = MT * 32;
    const int NHALF = MT / 2;                  // 2 for MT=4, 1 for MT=2
    const float* Af = (const float*)Asrc_;
    const unsigned short* A16 = (const unsigned short*)Asrc_;
    float* Cf = (float*)C_;
    unsigned short* C16 = (unsigned short*)C_;
    unsigned short* AhS = SH;                  // ROWS*40
    unsigned short* BhS = SH + ROWS * 40;      // 64*40
    unsigned short* AlS = SPLIT ? SH + ROWS * 40 + 2560 : SH;
    unsigned short* BlS = SPLIT ? SH + 2 * ROWS * 40 + 2560 : SH;
    int tid = threadIdx.x;
    int qq = nwg >> 3, rr = nwg & 7;
    int xcd = bid & 7, ixw = bid >> 3;
    int work = (xcd < rr) ? (xcd * (qq + 1) + ixw) : (rr * (qq + 1) + (xcd - rr) * qq + ixw);
    int bx = work / gy;
    int by = work - bx * gy;
    int m0 = bx * ROWS;
    int n0 = by * 64;
    int wave = tid >> 6, lane = tid & 63;
    int wm = (wave >> 1) * (MT * 16), wn = (wave & 1) * 32;   // group stride = MT*16
    int l15 = lane & 15, quad = lane >> 4;
    int lk = quad * 8, lk4 = quad * 4;
    fx4 acc[MT][2];
    #pragma unroll
    for (int a = 0; a < MT; a++)
        #pragma unroll
        for (int b = 0; b < 2; b++)
            acc[a][b] = (fx4){0.f, 0.f, 0.f, 0.f};

    int mm = tid & (ROWS - 1);
    int kpb = tid / ROWS;
    int gm = m0 + mm;
    int oj = 0, oi = 0, cA = 0, kfA = 0;
    size_t abase = 0;
    if (AMODE == 1) { oj = gm & ((1 << wshift) - 1); oi = gm >> wshift; }
    if (AMODE == 2) { oj = gm & 255; oi = gm >> 8; }
    if (AMODE == 3) abase = (size_t)gm * K;
    if (AMODE == 7) { cA = gm / 65; kfA = gm - cA * 65; }
    if (AMODE == 9) { cA = gm / 65; kfA = gm - cA * 65; }

    for (int kb = 0; kb < K; kb += 32) {
        if (AMODE == 3 && ABF16 && !SPLIT) {
            #pragma unroll
            for (int half = 0; half < NHALF; half++) {
                int off = (kpb * NHALF + half) * 8;
                sh8 hv = *(const sh8*)(const void*)&A16[abase + kb + off];
                *(sh8*)(void*)&AhS[mm * 40 + off] = hv;
            }
        } else {
            #pragma unroll
            for (int half = 0; half < NHALF; half++) {
                sh8 hv, lv;
                #pragma unroll
                for (int tt = 0; tt < 4; tt++) {
                    int kp = (kpb * NHALF + half) * 4 + tt;
                    int k0 = kb + kp * 2;
                    unsigned short h0, h1;
                    if (ABF16) {
                        size_t ad0, ad1;
                        if (AMODE == 0) {
                            ad0 = (size_t)k0 * M + gm;
                            ad1 = ad0 + M;
                        } else if (AMODE == 1) {
                            int c = k0 & ((1 << cshift) - 1);
                            int dydx = k0 >> cshift;
                            int dy = dydx >> 1, dx = dydx & 1;
                            size_t pix = (size_t)(2 * oi + dy) * srcW + (2 * oj + dx);
                            size_t plane = (size_t)srcW * srcW;
                            ad0 = (size_t)c * plane + pix;
                            ad1 = ad0 + plane;
                        } else if (AMODE == 3) {
                            ad0 = abase + k0;
                            ad1 = ad0 + 1;
                        } else {               // AMODE 7
                            int t0 = k0 & 127, hf = k0 >> 7;
                            ad0 = (size_t)(cA * 128 + t0) * 256 + hf * 128 + kfA;
                            ad1 = ad0 + 256;
                        }
                        h0 = A16[ad0];
                        h1 = A16[ad1];
                    } else {
                        float a0, a1;
                        if (AMODE == 2) {
                            if (k0 < 12) {
                                int d0 = k0 / 3, c0 = k0 - d0 * 3;
                                int k1 = k0 + 1;
                                int d1x = k1 / 3, c1 = k1 - d1x * 3;
                                a0 = Af[(size_t)c0 * NPIX + (size_t)(2 * oi + (d0 >> 1)) * 512 + 2 * oj + (d0 & 1)];
                                a1 = Af[(size_t)c1 * NPIX + (size_t)(2 * oi + (d1x >> 1)) * 512 + 2 * oj + (d1x & 1)];
                            } else { a0 = 0.f; a1 = 0.f; }
                        } else if (AMODE == 9) {
                            size_t ad = (size_t)cA * 16640 + (size_t)k0 * 65 + kfA;
                            float re0 = Af[ad], im0 = Af[ad + 2129920];
                            float re1 = Af[ad + 65], im1 = Af[ad + 65 + 2129920];
                            a0 = sqrtf(re0 * re0 + im0 * im0);
                            a1 = sqrtf(re1 * re1 + im1 * im1);
                        } else {
                            size_t ad0 = (size_t)k0 * M + gm;
                            a0 = Af[ad0];
                            a1 = Af[ad0 + M];
                        }
                        h0 = f2bf(a0);
                        h1 = f2bf(a1);
                        if (SPLIT) {
                            lv[tt * 2] = (short)f2bf(a0 - bf2f(h0));
                            lv[tt * 2 + 1] = (short)f2bf(a1 - bf2f(h1));
                        }
                    }
                    hv[tt * 2] = (short)h0;
                    hv[tt * 2 + 1] = (short)h1;
                }
                int coff = (kpb * NHALF + half) * 8;
                *(sh8*)(void*)&AhS[mm * 40 + coff] = hv;
                if (SPLIT) *(sh8*)(void*)&AlS[mm * 40 + coff] = lv;
            }
        }
        {
            int n = tid >> 2, seg = tid & 3;
            size_t gb = (size_t)(n0 + n) * K + kb + seg * 8;
            *(sh8*)(void*)&BhS[n * 40 + seg * 8] = *(const sh8*)(const void*)&Bh[gb];
            if (SPLIT) *(sh8*)(void*)&BlS[n * 40 + seg * 8] = *(const sh8*)(const void*)&Bl[gb];
        }
        __syncthreads();
        sh8 af[MT], bf[2], afl[MT], bfl[2];
        #pragma unroll
        for (int mt = 0; mt < MT; mt++) {
            af[mt] = *(const sh8*)(const void*)&AhS[(wm + mt * 16 + l15) * 40 + lk];
            if (SPLIT) afl[mt] = *(const sh8*)(const void*)&AlS[(wm + mt * 16 + l15) * 40 + lk];
        }
        #pragma unroll
        for (int nt = 0; nt < 2; nt++) {
            bf[nt] = *(const sh8*)(const void*)&BhS[(wn + nt * 16 + l15) * 40 + lk];
            if (SPLIT) bfl[nt] = *(const sh8*)(const void*)&BlS[(wn + nt * 16 + l15) * 40 + lk];
        }
        #pragma unroll
        for (int mt = 0; mt < MT; mt++)
            #pragma unroll
            for (int nt = 0; nt < 2; nt++) {
                acc[mt][nt] = __builtin_amdgcn_mfma_f32_16x16x32_bf16(af[mt], bf[nt], acc[mt][nt], 0, 0, 0);
                if (SPLIT) {
                    acc[mt][nt] = __builtin_amdgcn_mfma_f32_16x16x32_bf16(af[mt], bfl[nt], acc[mt][nt], 0, 0, 0);
                    acc[mt][nt] = __builtin_amdgcn_mfma_f32_16x16x32_bf16(afl[mt], bf[nt], acc[mt][nt], 0, 0, 0);
                }
            }
        __syncthreads();
    }
    #pragma unroll
    for (int nt = 0; nt < 2; nt++) {
        int n = n0 + wn + nt * 16 + l15;
        float bs = bias[n];
        #pragma unroll
        for (int mt = 0; mt < MT; mt++) {
            int mbase = m0 + wm + mt * 16 + lk4;
            if (TSTORE) {
                #pragma unroll
                for (int r = 0; r < 4; r++) {
                    float q = acc[mt][nt][r] + bs;
                    if (LRELU) q = (q < 0.f) ? 0.1f * q : q;
                    if (CBF16) C16[(size_t)(mbase + r) * N + n] = f2bf(q);
                    else       Cf[(size_t)(mbase + r) * N + n] = q;
                }
            } else if (CBF16) {
                ush4 v;
                #pragma unroll
                for (int r = 0; r < 4; r++) {
                    float q = acc[mt][nt][r] + bs;
                    if (LRELU) q = (q < 0.f) ? 0.1f * q : q;
                    v[r] = f2bf(q);
                }
                *(ush4*)(void*)&C16[(size_t)n * M + mbase] = v;
            } else {
                float4 v;
                float* vp = (float*)&v;
                #pragma unroll
                for (int r = 0; r < 4; r++) {
                    float q = acc[mt][nt][r] + bs;
                    if (LRELU) q = (q < 0.f) ? 0.1f * q : q;
                    vp[r] = q;
                }
                *(float4*)&Cf[(size_t)n * M + mbase] = v;
            }
        }
    }
}

// single-GEMM wrapper
template<int AMODE, int SPLIT, int LRELU, int TSTORE, int ABF16, int CBF16, int MT>
__global__ __launch_bounds__(256) void k_mmcf(const void* __restrict__ Asrc_,
                                              const unsigned short* __restrict__ Bh,
                                              const unsigned short* __restrict__ Bl,
                                              const float* __restrict__ bias, void* __restrict__ C_,
                                              int M, int N, int K, int cshift, int wshift, int srcW,
                                              int gy) {
    __shared__ unsigned short SH[SPLIT ? (2 * MT * 32 * 40 + 5120) : (MT * 32 * 40 + 2560)];
    mm_body<AMODE, SPLIT, LRELU, TSTORE, ABF16, CBF16, MT>(SH, Asrc_, Bh, Bl, bias, C_,
                                                           M, N, K, cshift, wshift, srcW, gy,
                                                           (int)blockIdx.x, (int)gridDim.x);
}

// d1 GEMM + 1 extra block reducing blockmax -> gmax
__global__ __launch_bounds__(256) void k_d1(const float* __restrict__ x,
                                            const unsigned short* __restrict__ d1ch,
                                            const float* __restrict__ b1c, unsigned short* __restrict__ xd1,
                                            const float* __restrict__ blockmax, int* __restrict__ gmax) {
    if (blockIdx.x == 1024) {
        __shared__ float red[256];
        int tid = threadIdx.x;
        red[tid] = fmaxf(blockmax[tid], blockmax[tid + 256]);
        __syncthreads();
        for (int s = 128; s > 0; s >>= 1) {
            if (tid < s) red[tid] = fmaxf(red[tid], red[tid + s]);
            __syncthreads();
        }
        if (tid == 0) gmax[0] = __float_as_int(red[0]);
        return;
    }
    __shared__ unsigned short SH[7680];
    mm_body<2, 0, 0, 0, 0, 1, 4>(SH, x, d1ch, nullptr, b1c, xd1, 65536, 128, 32, 0, 0, 0, 2,
                                 (int)blockIdx.x, 1024);
}

// F1 (1024 blocks) || sp1 (512 blocks)
__global__ __launch_bounds__(256) void k_dualA(const unsigned short* __restrict__ xd2,
                                               const unsigned short* __restrict__ BfH,
                                               const float* __restrict__ zbias, unsigned short* __restrict__ F1T,
                                               const unsigned short* __restrict__ s1h,
                                               const float* __restrict__ b_sp1, unsigned short* __restrict__ s1) {
    __shared__ unsigned short SH[7680];
    if (blockIdx.x < 1024)
        mm_body<3, 0, 0, 1, 1, 1, 4>(SH, xd2, BfH, nullptr, zbias, F1T, 32768, 256, 128, 0, 0, 0, 4,
                                     (int)blockIdx.x, 1024);
    else
        mm_body<0, 0, 1, 0, 1, 1, 4>(SH, xd2, s1h, nullptr, b_sp1, s1, 16384, 256, 256, 0, 0, 0, 4,
                                     (int)blockIdx.x - 1024, 512);
}

// F2 (520 blocks) || g4s (128 blocks)
__global__ __launch_bounds__(256) void k_dualB(const unsigned short* __restrict__ F1T,
                                               const unsigned short* __restrict__ BfcH,
                                               const float* __restrict__ zbias, float* __restrict__ F2C,
                                               const unsigned short* __restrict__ s1,
                                               const unsigned short* __restrict__ Wg,
                                               const float* __restrict__ bgc, float* __restrict__ g4s) {
    __shared__ unsigned short SH[7680];
    if (blockIdx.x < 520)
        mm_body<7, 0, 0, 0, 1, 0, 4>(SH, F1T, BfcH, nullptr, zbias, F2C, 16640, 256, 256, 0, 0, 0, 4,
                                     (int)blockIdx.x, 520);
    else
        mm_body<0, 0, 0, 0, 1, 0, 4>(SH, s1, Wg, nullptr, bgc, g4s, 16384, 64, 256, 0, 0, 0, 1,
                                     (int)blockIdx.x - 520, 128);
}

// ---------------------------------------------------------------- z = a*(cos a, sin a), flattened full-wave, bf16
__global__ __launch_bounds__(256) void k_zbuild(const float* __restrict__ A2, unsigned short* __restrict__ Z) {
    int idx = blockIdx.x * 256 + threadIdx.x;   // < 2129920
    int ct = idx / 65, kf = idx - ct * 65;
    int c = ct >> 7, t = ct & 127;
    float a = A2[idx];
    float s_, c_;
    sincosf(a, &s_, &c_);
    size_t m = (size_t)c * 65 + kf;
    Z[(size_t)t * 16640 + m] = f2bf(a * c_);
    Z[2129920 + (size_t)t * 16640 + m] = f2bf(a * s_);
}

// ---------------------------------------------------------------- P[r][kf][ht] = sum_c W21c[r][c] * I1T[(c,kf)][ht]  (coalesced in ht)
__global__ __launch_bounds__(256) void k_pfold(const unsigned short* __restrict__ I1T,
                                               const float* __restrict__ W21c, float* __restrict__ P) {
    __shared__ float wa[768];
    int kf = blockIdx.x, tid = threadIdx.x;
    for (int t = tid; t < 768; t += 256) wa[t] = W21c[t];
    __syncthreads();
    float a0 = 0.f, a1 = 0.f, a2 = 0.f;
    #pragma unroll 4
    for (int c = 0; c < 256; c++) {
        float v = bf2f(I1T[(size_t)(c * 65 + kf) * 256 + tid]);
        a0 += wa[c] * v;
        a1 += wa[256 + c] * v;
        a2 += wa[512 + c] * v;
    }
    P[(size_t)(0 * 65 + kf) * 256 + tid] = a0;
    P[(size_t)(1 * 65 + kf) * 256 + tid] = a1;
    P[(size_t)(2 * 65 + kf) * 256 + tid] = a2;
}

// ---------------------------------------------------------------- h3s[r][tau][col] = sum_k Birf[k][col] * P[r][kf(k)][hf(k),tau] + b21c[r]
__global__ __launch_bounds__(128) void k_h3f(const float* __restrict__ P, const float* __restrict__ Birf,
                                             const float* __restrict__ b21c, float* __restrict__ h3s) {
    __shared__ float sp[390];
    __shared__ float bs[3];
    int tau = blockIdx.x, col = threadIdx.x;
    for (int t = col; t < 390; t += 128) {
        int r = t / 130, rem = t - r * 130;
        int hf = rem / 65, kf = rem - hf * 65;
        sp[t] = P[(size_t)(r * 65 + kf) * 256 + hf * 128 + tau];
    }
    if (col < 3) bs[col] = b21c[col];
    __syncthreads();
    float f0 = 0.f, f1 = 0.f, f2 = 0.f;
    for (int k0 = 0; k0 < 130; k0++) {
        float w = Birf[k0 * 128 + col];
        f0 += w * sp[k0];
        f1 += w * sp[130 + k0];
        f2 += w * sp[260 + k0];
    }
    size_t q = (size_t)tau * 128 + col;
    h3s[q]         = f0 + bs[0];
    h3s[16384 + q] = f1 + bs[1];
    h3s[32768 + q] = f2 + bs[2];
}

// ---------------------------------------------------------------- final fused stage @512^2 (y-interp staged in LDS)
__global__ __launch_bounds__(256) void k_final(const float* __restrict__ x,
                                               const float* __restrict__ dark, const int* __restrict__ gmax,
                                               const float* __restrict__ wcf1, const float* __restrict__ bcf1,
                                               const float* __restrict__ Wc, const float* __restrict__ bc,
                                               const float* __restrict__ g4s, const float* __restrict__ h3s,
                                               float* __restrict__ out) {
    __shared__ float idimt[32], w1[192], b1[64], wb[192], bcs[3], posy[16];
    __shared__ float gyr[64][68];
    __shared__ float hyr[3][68];
    int tid = threadIdx.x;
    int bid = blockIdx.x;
    int i = bid >> 1;
    int j0 = (bid & 1) << 8;
    int j = j0 + tid;
    int p = (i << 9) + j;

    const float scale = 2.f * PI_F;
    float inv511 = scale / (511.f + 1e-6f);
    float ye = (float)i * inv511;

    if (tid < 32) idimt[tid] = 1.f / powf(10000.f, (float)(2 * (tid >> 1)) / 32.f);
    if (tid < 192) w1[tid] = wcf1[tid];
    if (tid < 64) b1[tid] = bcf1[tid];
    if (tid < 192) { int r = tid / 64, c = tid - (tid / 64) * 64; wb[tid] = Wc[r * 128 + 64 + c]; }
    if (tid < 3) bcs[tid] = bc[tid];
    __syncthreads();
    if (tid >= 32 && tid < 48) {
        int c = tid - 32;
        float e = ye * idimt[c];
        posy[c] = ((c & 1) == 0) ? __sinf(e) : __cosf(e);
    }

    int ky = i >> 2, ry = i & 3;
    int ym = (ky > 0) ? ky - 1 : 0, yp = (ky < 127) ? ky + 1 : 127;
    float wy0 = (ry == 0) ? .375f : (ry == 1) ? .1875f : (ry == 2) ? .0625f : 0.f;
    float wy1 = (ry == 0 || ry == 3) ? .625f : .75f;
    float wy2 = (ry == 0) ? 0.f : (ry == 1) ? .0625f : (ry == 2) ? .1875f : .375f;
    int base = j0 >> 2;
    int r0 = ym * 128, r1 = ky * 128, r2 = yp * 128;
    for (int idx = tid; idx < 64 * 66; idx += 256) {
        int c = idx / 66, t = idx - c * 66;
        int col = base - 1 + t;
        col = (col < 0) ? 0 : (col > 127) ? 127 : col;
        const float* gp = g4s + (size_t)c * 16384;
        gyr[c][t] = wy0 * gp[r0 + col] + wy1 * gp[r1 + col] + wy2 * gp[r2 + col];
    }
    for (int idx = tid; idx < 3 * 66; idx += 256) {
        int c = idx / 66, t = idx - c * 66;
        int col = base - 1 + t;
        col = (col < 0) ? 0 : (col > 127) ? 127 : col;
        const float* hp = h3s + (size_t)c * 16384;
        hyr[c][t] = wy0 * hp[r0 + col] + wy1 * hp[r1 + col] + wy2 * hp[r2 + col];
    }
    __syncthreads();

    float xe = (float)j * inv511;
    float gm = __int_as_float(gmax[0]);
    float ze = dark[p] / (gm + 1e-6f) * scale;
    float x0 = x[p], x1 = x[p + NPIX], x2 = x[p + 2 * NPIX];

    int rx = j & 3;
    int tx = tid >> 2;
    float wx0 = (rx == 0) ? .375f : (rx == 1) ? .1875f : (rx == 2) ? .0625f : 0.f;
    float wx1 = (rx == 0 || rx == 3) ? .625f : .75f;
    float wx2 = (rx == 0) ? 0.f : (rx == 1) ? .0625f : (rx == 2) ? .1875f : .375f;

    float a0 = 0.f, a1 = 0.f, a2 = 0.f;
    #pragma unroll 1
    for (int c = 0; c < 64; c++) {
        float pos;
        if (c < 16)      { float e = xe * idimt[c];      pos = ((c & 1) == 0) ? __sinf(e) : __cosf(e); }
        else if (c < 32) { pos = posy[c - 16]; }
        else             { float e = ze * idimt[c - 32]; pos = ((c & 1) == 0) ? __sinf(e) : __cosf(e); }
        float ape = pos + w1[c * 3] * x0 + w1[c * 3 + 1] * x1 + w1[c * 3 + 2] * x2 + b1[c];
        float gv = wx0 * gyr[c][tx] + wx1 * gyr[c][tx + 1] + wx2 * gyr[c][tx + 2];
        float s = gv * ape;
        a0 += wb[c] * s; a1 += wb[64 + c] * s; a2 += wb[128 + c] * s;
    }
    float f0 = wx0 * hyr[0][tx] + wx1 * hyr[0][tx + 1] + wx2 * hyr[0][tx + 2];
    float f1 = wx0 * hyr[1][tx] + wx1 * hyr[1][tx + 1] + wx2 * hyr[1][tx + 2];
    float f2 = wx0 * hyr[2][tx] + wx1 * hyr[2][tx + 1] + wx2 * hyr[2][tx + 2];
    out[p]            = a0 + f0 + bcs[0] + x0;
    out[NPIX + p]     = a1 + f1 + bcs[1] + x1;
    out[2 * NPIX + p] = a2 + f2 + bcs[2] + x2;
}

// ================================================================ launcher
extern "C" void kernel_launch(void* const* d_in, const int* in_sizes, int n_in,
                              void* d_out, int out_size, void* d_ws, size_t ws_size,
                              hipStream_t stream) {
    const float* x      = (const float*)d_in[0];
    const float* w_cf1  = (const float*)d_in[1];  const float* b_cf1 = (const float*)d_in[2];
    const float* w_e1   = (const float*)d_in[3];  const float* b_e1  = (const float*)d_in[4];
    const float* w_e2   = (const float*)d_in[5];  const float* b_e2  = (const float*)d_in[6];
    const float* w_d1   = (const float*)d_in[7];  const float* b_d1  = (const float*)d_in[8];
    const float* w_d2   = (const float*)d_in[9];  const float* b_d2  = (const float*)d_in[10];
    // 11..14: pha branch is dead code in the reference
    const float* w_amp1 = (const float*)d_in[15]; const float* b_amp1 = (const float*)d_in[16];
    const float* w_amp2 = (const float*)d_in[17]; const float* b_amp2 = (const float*)d_in[18];
    const float* w_sp1  = (const float*)d_in[19]; const float* b_sp1  = (const float*)d_in[20];
    const float* w_sp2  = (const float*)d_in[21]; const float* b_sp2  = (const float*)d_in[22];
    const float* w_u1   = (const float*)d_in[23]; const float* b_u1   = (const float*)d_in[24];
    const float* w_u2   = (const float*)d_in[25]; const float* b_u2   = (const float*)d_in[26];
    const float* w_u3   = (const float*)d_in[27]; const float* b_u3   = (const float*)d_in[28];
    const float* w_u4   = (const float*)d_in[29]; const float* b_u4   = (const float*)d_in[30];
    const float* w_cf2  = (const float*)d_in[31]; const float* b_cf2  = (const float*)d_in[32];
    const float* w_cf3  = (const float*)d_in[33]; const float* b_cf3  = (const float*)d_in[34];
    float* out = (float*)d_out;

    char* ws = (char*)d_ws;
    constexpr size_t MiB = 1ull << 20;
    float*  dark   = (float*)(ws + 0 * MiB);
    int*    gmax   = (int*)  (ws + 2 * MiB);
    float*  Wc     = (float*)(ws + 2 * MiB + 1024);
    float*  bc     = (float*)(ws + 2 * MiB + 2560);
    float*  W21c   = (float*)(ws + 2 * MiB + 4096);
    float*  b21c   = (float*)(ws + 2 * MiB + 7168);
    float*  blockmax = (float*)(ws + 2 * MiB + 8192);             // [512]
    unsigned short* d1ch = (unsigned short*)(ws + 3 * MiB);       // bf16 [128][32]
    float*  b1c    = (float*)(ws + 3 * MiB + 16384);
    unsigned short* Wg = (unsigned short*)(ws + 3 * MiB + 131072);// bf16 [64][256]
    float*  bgc    = (float*)(ws + 3 * MiB + 196608);
    unsigned short* xd1 = (unsigned short*)(ws + 67 * MiB);   // bf16 [128][65536] = 16 MiB
    unsigned short* xd2 = (unsigned short*)(ws + 99 * MiB);   // bf16 [256][16384] =  8 MiB
    unsigned short* F1T = (unsigned short*)(ws + 115 * MiB);  // bf16 [32768][256] = 16 MiB
    float*  F2C    = (float*)(ws + 147 * MiB);                // fp32 (feeds sqrt fused in amp1)
    float*  A1     = (float*)(ws + 173 * MiB);
    float*  A2     = (float*)(ws + 182 * MiB);
    unsigned short* Zbuf = (unsigned short*)(ws + 115 * MiB); // bf16 (F1T dead after F2)
    unsigned short* I1T  = (unsigned short*)(ws + 132 * MiB); // bf16 [16640][256] = 8.5 MiB
    float*  P      = (float*)(ws + 149 * MiB);                // fp32 [3][65][256]
    float*  h3s    = (float*)(ws + 11 * MiB);                 // fp32 [3][16384]
    unsigned short* s1 = (unsigned short*)(ws + 31 * MiB);    // bf16 [256][16384] = 8 MiB
    float*  g4s    = (float*)(ws + 87 * MiB);                 // fp32 [64][16384]
    unsigned short* wb16 = (unsigned short*)(ws + 192 * MiB);
    unsigned short* d2h = wb16 + 65536,   * d2l = wb16 + 196608;
    unsigned short* a1h = wb16 + 327680,  * a1l = wb16 + 393216;
    unsigned short* a2h = wb16 + 458752,  * a2l = wb16 + 524288;
    unsigned short* s1h = wb16 + 589824;
    unsigned short* BfH = wb16 + 786432,  * BfL = wb16 + 819200;
    unsigned short* BfcH = wb16 + 851968, * BfcL = wb16 + 917504;
    unsigned short* BicH = wb16 + 983040, * BicL = wb16 + 1048576;
    float* zbias = (float*)(ws + 195 * MiB + 512 * 1024);
    float* Birf  = (float*)(ws + 196 * MiB);                  // fp32 [160][128]

    // 1) mega prep: weights + tables + composes + dark (one launch)
    k_prep<<<2594, 256, 0, stream>>>(
        x, dark, blockmax,
        w_d2, d2h, d2l, w_amp1, a1h, a1l, w_amp2, a2h, a2l, w_sp1, s1h,
        BfH, BfL, BfcH, BfcL, BicH, BicL, Birf, zbias,
        w_e1, b_e1, w_e2, b_e2, w_d1, b_d1, d1ch, b1c,
        w_u3, w_u4, b_u3, b_u4, w_sp2, b_sp2, Wg, bgc,
        w_cf2, b_cf2, w_cf3, b_cf3, w_u2, b_u2, w_u1, b_u1,
        Wc, bc, W21c, b21c);

    // 2) d1 (+ gmax reduce rides along) ; d2
    k_d1<<<1025, 256, 0, stream>>>(x, d1ch, b1c, xd1, blockmax, gmax);
    k_mmcf<1, 0, 0, 0, 1, 1, 4><<<512, 256, 0, stream>>>(xd1, d2h, nullptr, b_d2, xd2, 16384, 256, 512, 7, 7, 256, 4);

    // 3) F1 || sp1 ; F2 || g4s  (spat path overlapped with FFT path)
    k_dualA<<<1536, 256, 0, stream>>>(xd2, BfH, zbias, F1T, s1h, b_sp1, s1);
    k_dualB<<<648, 256, 0, stream>>>(F1T, BfcH, zbias, F2C, s1, Wg, bgc, g4s);

    // 4) amp MLP at MT=2 (64-row tiles, 520 blocks, 2 blocks/CU) ; zbuild ; I1
    k_mmcf<9, 1, 1, 0, 0, 0, 2><<<520, 256, 0, stream>>>(F2C, a1h, a1l, b_amp1, A1, 8320, 256, 256, 0, 0, 0, 4);
    k_mmcf<0, 1, 0, 0, 0, 0, 2><<<520, 256, 0, stream>>>(A1, a2h, a2l, b_amp2, A2, 8320, 256, 256, 0, 0, 0, 4);
    k_zbuild<<<8320, 256, 0, stream>>>(A2, Zbuf);
    k_mmcf<0, 0, 0, 1, 1, 1, 4><<<520, 256, 0, stream>>>(Zbuf, BicH, nullptr, zbias, I1T, 16640, 256, 256, 0, 0, 0, 4);

    // 5) factored h3: P = W21c ∘ I1T (coalesced) ; h3s = Birf ∘ P
    k_pfold<<<65, 256, 0, stream>>>(I1T, W21c, P);
    k_h3f<<<128, 128, 0, stream>>>(P, Birf, b21c, h3s);

    // 6) final fused stage
    k_final<<<1024, 256, 0, stream>>>(x, dark, gmax, w_cf1, b_cf1, Wc, bc, g4s, h3s, out);
}